// Round 1
// baseline (127.122 us; speedup 1.0000x reference)
//
#include <hip/hip_runtime.h>

#define TILE 32
#define HALO 2
#define LW (TILE + 2 * HALO)   // 36

// Per-pixel stencil: loss(p,t,q,s) = bce(p,t) / (mutual + pairwise + eps)
// Combined weights: inner 3x3 ring gets 1/9 (i=1) + 0.5/25 (i=2); outer ring 0.5/25.
// OOB patch positions contribute w * 1.0 (the vm mask in the reference).

__global__ __launch_bounds__(256) void scloss_main(
    const float* __restrict__ pred, const float* __restrict__ target,
    double* __restrict__ partial, int B, int H, int W) {
    __shared__ float sh_p[LW * LW];
    __shared__ float sh_t[LW * LW];
    __shared__ float sh_g[LW * LW];   // sigmoid(pred); -1 marks out-of-bounds

    const int tilesX = W / TILE;
    const int tilesY = H / TILE;
    const int tilesPer = tilesX * tilesY;
    const int b = blockIdx.x / tilesPer;
    const int tile = blockIdx.x % tilesPer;
    const int ty0 = (tile / tilesX) * TILE;
    const int tx0 = (tile % tilesX) * TILE;

    const float* pbase = pred + (size_t)b * H * W;
    const float* tbase = target + (size_t)b * H * W;

    const int tid = threadIdx.x;

    // Stage tile + halo; compute sigmoid once per cell.
    for (int idx = tid; idx < LW * LW; idx += 256) {
        const int cy = idx / LW, cx = idx % LW;
        const int gy = ty0 + cy - HALO;
        const int gx = tx0 + cx - HALO;
        float p = 0.f, t = 0.f, g = -1.f;
        if (gy >= 0 && gy < H && gx >= 0 && gx < W) {
            p = pbase[gy * W + gx];
            t = tbase[gy * W + gx];
            g = __fdividef(1.f, 1.f + __expf(-p));
        }
        sh_p[idx] = p; sh_t[idx] = t; sh_g[idx] = g;
    }
    __syncthreads();

    const float W_IN  = (1.0f / 9.0f) + 0.02f;  // 3x3 + weighted 5x5 share
    const float W_OUT = 0.02f;                  // 0.5 / 25

    float acc = 0.f;
    const int px = tid & 31;
    const int py0 = tid >> 5;   // 0..7; each thread does 4 rows stride 8

    #pragma unroll
    for (int r = 0; r < 4; ++r) {
        const int cy = py0 + r * 8 + HALO;
        const int cx = px + HALO;
        const float p  = sh_p[cy * LW + cx];
        const float t  = sh_t[cy * LW + cx];
        const float gp = sh_g[cy * LW + cx];
        // bce = softplus(p) - p*t  (stable softplus)
        const float bce = fmaxf(p, 0.f) + __logf(1.f + __expf(-fabsf(p))) - p * t;

        #pragma unroll
        for (int dy = -2; dy <= 2; ++dy) {
            #pragma unroll
            for (int dx = -2; dx <= 2; ++dx) {
                const bool inner = (dy >= -1) & (dy <= 1) & (dx >= -1) & (dx <= 1);
                const float w = inner ? W_IN : W_OUT;
                const int nidx = (cy + dy) * LW + (cx + dx);
                const float gq = sh_g[nidx];
                if (gq < 0.f) {          // padded position: loss = 1.0
                    acc += w;
                } else {
                    const float q = sh_p[nidx];
                    const float s = sh_t[nidx];
                    const float joint = p * q;
                    const float lab = t * s;
                    const float spj = fmaxf(joint, 0.f) +
                                      __logf(1.f + __expf(-fabsf(joint)));
                    const float mutual = spj - joint * lab;
                    const float pw = __expf(-gp * gq);
                    acc += w * __fdividef(bce, mutual + pw + 1e-6f);
                }
            }
        }
    }

    // Block reduction: wave shuffle, then cross-wave via LDS in double.
    #pragma unroll
    for (int off = 32; off > 0; off >>= 1)
        acc += __shfl_down(acc, off, 64);
    __shared__ double wsum[4];
    if ((tid & 63) == 0) wsum[tid >> 6] = (double)acc;
    __syncthreads();
    if (tid == 0)
        partial[blockIdx.x] = wsum[0] + wsum[1] + wsum[2] + wsum[3];
}

__global__ __launch_bounds__(256) void scloss_reduce(
    const double* __restrict__ partial, int n, float* __restrict__ out,
    double inv_cnt) {
    __shared__ double sm[256];
    double s = 0.0;
    for (int i = threadIdx.x; i < n; i += 256) s += partial[i];
    sm[threadIdx.x] = s;
    __syncthreads();
    for (int off = 128; off > 0; off >>= 1) {
        if (threadIdx.x < off) sm[threadIdx.x] += sm[threadIdx.x + off];
        __syncthreads();
    }
    if (threadIdx.x == 0) out[0] = (float)(sm[0] * inv_cnt);
}

extern "C" void kernel_launch(void* const* d_in, const int* in_sizes, int n_in,
                              void* d_out, int out_size, void* d_ws, size_t ws_size,
                              hipStream_t stream) {
    const float* pred   = (const float*)d_in[0];
    const float* target = (const float*)d_in[1];
    float* out = (float*)d_out;

    const int H = 512, W = 512;
    const int B = in_sizes[0] / (H * W);

    double* partial = (double*)d_ws;
    const int nblocks = B * (H / TILE) * (W / TILE);   // 2048 for B=8

    scloss_main<<<nblocks, 256, 0, stream>>>(pred, target, partial, B, H, W);
    scloss_reduce<<<1, 256, 0, stream>>>(partial, nblocks, out,
                                         1.0 / ((double)B * H * W));
}

// Round 3
// 104.066 us; speedup vs baseline: 1.2216x; 1.2216x over previous
//
#include <hip/hip_runtime.h>

#define TILE 32
#define HALO 2
#define LH (TILE + HALO)        // 34 rows: tile rows 0..31 + bottom halo (no top halo needed)
#define LW (TILE + 2 * HALO)    // 36 cols: left/right halo 2
#define EPS 1e-6f

// loss(a<-b) = bce_a / D(a,b);  D symmetric in (a,b).
// Grand sum = sum_a [ w0*bce_a/D(a,a) ]
//           + sum_{unordered pairs (a,b)} [ both in-bounds ? w*(bce_a+bce_b)/D : w per directed OOB ]
// Weights: inner 3x3 ring 1/9 + 0.5/25, outer 5x5 ring 0.5/25.

__device__ __forceinline__ float softplus_f(float x) {
    return fmaxf(x, 0.f) + __logf(1.f + __expf(-fabsf(x)));
}

constexpr float W_IN  = 1.0f / 9.0f + 0.02f;
constexpr float W_OUT = 0.02f;

// Half-plane offsets (lexicographic: (0,1),(0,2), then rows +1,+2)
__constant__ const int   c_dy[12] = {0, 0, 1, 1, 1, 1, 1, 2, 2, 2, 2, 2};
__constant__ const int   c_dx[12] = {1, 2, -2, -1, 0, 1, 2, -2, -1, 0, 1, 2};
__constant__ const float c_w[12]  = {W_IN, W_OUT, W_OUT, W_IN, W_IN, W_IN,
                                     W_OUT, W_OUT, W_OUT, W_OUT, W_OUT, W_OUT};

__global__ __launch_bounds__(256) void scloss_main(
    const float* __restrict__ pred, const float* __restrict__ target,
    double* __restrict__ partial, int B, int H, int W) {
    __shared__ float4 sh[LH * LW];   // (p, t, sigmoid(p), bce); z = -1 marks OOB

    const int tilesX = W / TILE;
    const int tilesPer = tilesX * (H / TILE);
    const int b = blockIdx.x / tilesPer;
    const int tile = blockIdx.x % tilesPer;
    const int ty0 = (tile / tilesX) * TILE;
    const int tx0 = (tile % tilesX) * TILE;

    const float* pbase = pred + (size_t)b * H * W;
    const float* tbase = target + (size_t)b * H * W;
    const int tid = threadIdx.x;

    // Stage cells: rows ty0..ty0+33, cols tx0-2..tx0+33; sigmoid+bce once per cell.
    for (int idx = tid; idx < LH * LW; idx += 256) {
        const int cy = idx / LW, cx = idx % LW;
        const int gy = ty0 + cy;
        const int gx = tx0 + cx - HALO;
        float p = 0.f, t = 0.f, g = -1.f, bce = 0.f;
        if (gy < H && gx >= 0 && gx < W) {   // gy >= 0 always (no top halo)
            p = pbase[gy * W + gx];
            t = tbase[gy * W + gx];
            g = __fdividef(1.f, 1.f + __expf(-p));
            bce = softplus_f(p) - p * t;
        }
        sh[idx] = make_float4(p, t, g, bce);
    }
    __syncthreads();

    const int px = tid & 31;
    const int py0 = tid >> 5;   // 0..7; each thread handles rows py0 + 8r
    float acc = 0.f;

    const bool negCheck = (ty0 == 0) || (tx0 == 0) || (tx0 + TILE == W);

    // Compile-time offsets for the unrolled pair loop (folds to imm-offset ds_read_b128).
    constexpr int pdy[12] = {0, 0, 1, 1, 1, 1, 1, 2, 2, 2, 2, 2};
    constexpr int pdx[12] = {1, 2, -2, -1, 0, 1, 2, -2, -1, 0, 1, 2};
    constexpr float pw12[12] = {W_IN, W_OUT, W_OUT, W_IN, W_IN, W_IN,
                                W_OUT, W_OUT, W_OUT, W_OUT, W_OUT, W_OUT};

    #pragma unroll
    for (int r = 0; r < 4; ++r) {
        const int ay = py0 + r * 8;                  // row within tile == staged row
        const float4* base = &sh[ay * LW + px + HALO];
        const float4 ca = base[0];

        // self term (offset 0,0): w0 * bce_a / D(a,a)
        {
            const float j = ca.x * ca.x;
            const float m = softplus_f(j) - j * (ca.y * ca.y);
            const float pw = __expf(-ca.z * ca.z);
            acc += __fdividef(W_IN * ca.w, m + pw + EPS);
        }

        // 12 half-plane pair terms, branchless OOB select.
        // OOB cells hold (0,0,-1,0): D = softplus(0) + exp(0) + eps > 0, no NaN.
        #pragma unroll
        for (int k = 0; k < 12; ++k) {
            const float w = pw12[k];
            const float4 cb = base[pdy[k] * LW + pdx[k]];
            const float j = ca.x * cb.x;
            const float m = softplus_f(j) - j * (ca.y * cb.y);
            const float pw = __expf(-ca.z * cb.z);
            const float pv = __fdividef(w * (ca.w + cb.w), m + pw + EPS);
            acc += (cb.z < 0.f) ? w : pv;
        }

        // Edge blocks only: a's directed terms toward OOB neighbors in the
        // NEGATIVE half-plane (the pair owner a-o doesn't exist there).
        if (negCheck) {
            const int gy = ty0 + ay, gx = tx0 + px;
            #pragma unroll
            for (int k = 0; k < 12; ++k) {
                const int ny = gy - c_dy[k], nx = gx - c_dx[k];
                if (ny < 0 || nx < 0 || nx >= W) acc += c_w[k];
            }
        }
    }

    // Block reduction: wave shuffle, then cross-wave via LDS in double.
    #pragma unroll
    for (int off = 32; off > 0; off >>= 1)
        acc += __shfl_down(acc, off, 64);
    __shared__ double wsum[4];
    if ((tid & 63) == 0) wsum[tid >> 6] = (double)acc;
    __syncthreads();
    if (tid == 0)
        partial[blockIdx.x] = wsum[0] + wsum[1] + wsum[2] + wsum[3];
}

__global__ __launch_bounds__(256) void scloss_reduce(
    const double* __restrict__ partial, int n, float* __restrict__ out,
    double inv_cnt) {
    __shared__ double sm[256];
    double s = 0.0;
    for (int i = threadIdx.x; i < n; i += 256) s += partial[i];
    sm[threadIdx.x] = s;
    __syncthreads();
    for (int off = 128; off > 0; off >>= 1) {
        if (threadIdx.x < off) sm[threadIdx.x] += sm[threadIdx.x + off];
        __syncthreads();
    }
    if (threadIdx.x == 0) out[0] = (float)(sm[0] * inv_cnt);
}

extern "C" void kernel_launch(void* const* d_in, const int* in_sizes, int n_in,
                              void* d_out, int out_size, void* d_ws, size_t ws_size,
                              hipStream_t stream) {
    const float* pred   = (const float*)d_in[0];
    const float* target = (const float*)d_in[1];
    float* out = (float*)d_out;

    const int H = 512, W = 512;
    const int B = in_sizes[0] / (H * W);

    double* partial = (double*)d_ws;
    const int nblocks = B * (H / TILE) * (W / TILE);   // 2048 for B=8

    scloss_main<<<nblocks, 256, 0, stream>>>(pred, target, partial, B, H, W);
    scloss_reduce<<<1, 256, 0, stream>>>(partial, nblocks, out,
                                         1.0 / ((double)B * H * W));
}

// Round 4
// 101.870 us; speedup vs baseline: 1.2479x; 1.0216x over previous
//
#include <hip/hip_runtime.h>

#define TILE 32
#define HALO 2
#define LH (TILE + HALO)        // 34 rows: tile + bottom halo (no top halo needed)
#define LW (TILE + 2 * HALO)    // 36 cols
#define EPS 1e-6f

// loss(a<-b) = bce_a / D(a,b);  D symmetric in (a,b) -> pair once, weight (bce_a+bce_b).
// Weights: inner 3x3 ring 1/9 + 0.5/25, outer 5x5 ring 0.5/25.
// Transcendental diet: hw v_exp only for e^{-|j|}; log1p and exp(-gg) by polynomial;
// one v_rcp per TWO pair terms.

constexpr float W_IN  = 1.0f / 9.0f + 0.02f;
constexpr float W_OUT = 0.02f;

// ln(1+u) for u in [0,1]: w=(u-0.5)*(2/3); ln1.5 + w - w^2/2 + ... - w^7/7. |err|~1.2e-4
__device__ __forceinline__ float log1p_poly(float u) {
    const float w = (u - 0.5f) * 0.6666666667f;
    float s = 0.14285714f;                      // 1/7
    s = __builtin_fmaf(s, w, -0.16666667f);
    s = __builtin_fmaf(s, w, 0.20f);
    s = __builtin_fmaf(s, w, -0.25f);
    s = __builtin_fmaf(s, w, 0.33333333f);
    s = __builtin_fmaf(s, w, -0.50f);
    s = __builtin_fmaf(s, w, 1.0f);
    return __builtin_fmaf(s, w, 0.40546511f);   // + ln(1.5)
}

// e^{-x} for x in [0,1]: z=x-0.5; e^{-0.5} * (1 - z + z^2/2 - z^3/6 + z^4/24 - z^5/120). |err|~4e-5
__device__ __forceinline__ float expneg01_poly(float x) {
    const float z = x - 0.5f;
    float s = -0.0083333333f;                   // -1/120
    s = __builtin_fmaf(s, z, 0.041666667f);
    s = __builtin_fmaf(s, z, -0.16666667f);
    s = __builtin_fmaf(s, z, 0.5f);
    s = __builtin_fmaf(s, z, -1.0f);
    s = __builtin_fmaf(s, z, 1.0f);
    return s * 0.60653066f;                     // * e^{-0.5}
}

// One directed-pair denominator/numerator. ca always in-bounds; cb.z<0 marks OOB
// (then the pair contributes exactly w: n=w, d=1).
__device__ __forceinline__ void pair_nd(const float4 ca, const float4 cb, float w,
                                        float& n, float& d) {
    const float j   = ca.x * cb.x;
    const float lab = ca.y * cb.y;
    const float u   = __expf(-fabsf(j));               // the one hw transcendental
    const float sp  = fmaxf(j, 0.f) + log1p_poly(u);   // softplus(j)
    const float m   = sp - j * lab;                    // mutual
    const float pw  = expneg01_poly(ca.z * cb.z);      // pairwise, arg in (0,1)
    const float dd  = m + pw + EPS;
    const float nn  = w * (ca.w + cb.w);
    const bool oob  = cb.z < 0.f;
    n = oob ? w : nn;
    d = oob ? 1.f : dd;
}

__global__ __launch_bounds__(256) void scloss_main(
    const float* __restrict__ pred, const float* __restrict__ target,
    float* __restrict__ out, int B, int H, int W, double inv_cnt) {
    __shared__ float4 sh[LH * LW];   // (p, t, sigmoid(p), bce); z=-1 marks OOB

    const int tilesX = W / TILE;
    const int tilesPer = tilesX * (H / TILE);
    const int b = blockIdx.x / tilesPer;
    const int tile = blockIdx.x % tilesPer;
    const int ty0 = (tile / tilesX) * TILE;
    const int tx0 = (tile % tilesX) * TILE;

    const float* pbase = pred + (size_t)b * H * W;
    const float* tbase = target + (size_t)b * H * W;
    const int tid = threadIdx.x;

    for (int idx = tid; idx < LH * LW; idx += 256) {
        const int cy = idx / LW, cx = idx % LW;
        const int gy = ty0 + cy;
        const int gx = tx0 + cx - HALO;
        float p = 0.f, t = 0.f, g = -1.f, bce = 0.f;
        if (gy < H && gx >= 0 && gx < W) {
            p = pbase[gy * W + gx];
            t = tbase[gy * W + gx];
            g = __builtin_amdgcn_rcpf(1.f + __expf(-p));           // sigmoid
            bce = fmaxf(p, 0.f) + log1p_poly(__expf(-fabsf(p))) - p * t;
        }
        sh[idx] = make_float4(p, t, g, bce);
    }
    __syncthreads();

    const int px = tid & 31;
    const int py0 = tid >> 5;
    float acc = 0.f;

    const bool negCheck = (ty0 == 0) || (tx0 == 0) || (tx0 + TILE == W);

    constexpr int pdy[12] = {0, 0, 1, 1, 1, 1, 1, 2, 2, 2, 2, 2};
    constexpr int pdx[12] = {1, 2, -2, -1, 0, 1, 2, -2, -1, 0, 1, 2};
    constexpr float pw12[12] = {W_IN, W_OUT, W_OUT, W_IN, W_IN, W_IN,
                                W_OUT, W_OUT, W_OUT, W_OUT, W_OUT, W_OUT};

    #pragma unroll
    for (int r = 0; r < 4; ++r) {
        const int ay = py0 + r * 8;
        const float4* base = &sh[ay * LW + px + HALO];
        const float4 ca = base[0];

        // self term: w0*bce/D(a,a).  pair_nd with cb=ca gives n=w*(2*bce) -> pass W_IN/2.
        {
            float n, d;
            pair_nd(ca, ca, W_IN * 0.5f, n, d);
            acc += n * __builtin_amdgcn_rcpf(d);
        }

        // 12 half-plane pairs, combined two at a time: one rcp per two terms.
        #pragma unroll
        for (int k = 0; k < 12; k += 2) {
            float n1, d1, n2, d2;
            pair_nd(ca, base[pdy[k] * LW + pdx[k]], pw12[k], n1, d1);
            pair_nd(ca, base[pdy[k + 1] * LW + pdx[k + 1]], pw12[k + 1], n2, d2);
            const float num = n1 * d2 + n2 * d1;
            acc += num * __builtin_amdgcn_rcpf(d1 * d2);
        }

        // Edge blocks: directed terms toward OOB neighbors in the negative half-plane.
        if (negCheck) {
            const int gy = ty0 + ay, gx = tx0 + px;
            #pragma unroll
            for (int k = 0; k < 12; ++k) {
                const int ny = gy - pdy[k], nx = gx - pdx[k];
                if (ny < 0 || nx < 0 || nx >= W) acc += pw12[k];
            }
        }
    }

    // Block reduction -> one float atomic per block (pre-scaled).
    #pragma unroll
    for (int off = 32; off > 0; off >>= 1)
        acc += __shfl_down(acc, off, 64);
    __shared__ double wsum[4];
    if ((tid & 63) == 0) wsum[tid >> 6] = (double)acc;
    __syncthreads();
    if (tid == 0) {
        const double s = wsum[0] + wsum[1] + wsum[2] + wsum[3];
        atomicAdd(out, (float)(s * inv_cnt));
    }
}

extern "C" void kernel_launch(void* const* d_in, const int* in_sizes, int n_in,
                              void* d_out, int out_size, void* d_ws, size_t ws_size,
                              hipStream_t stream) {
    const float* pred   = (const float*)d_in[0];
    const float* target = (const float*)d_in[1];
    float* out = (float*)d_out;

    const int H = 512, W = 512;
    const int B = in_sizes[0] / (H * W);
    const int nblocks = B * (H / TILE) * (W / TILE);   // 2048 for B=8

    hipMemsetAsync(out, 0, sizeof(float), stream);
    scloss_main<<<nblocks, 256, 0, stream>>>(pred, target, out, B, H, W,
                                             1.0 / ((double)B * H * W));
}

// Round 5
// 98.503 us; speedup vs baseline: 1.2905x; 1.0342x over previous
//
#include <hip/hip_runtime.h>

#define TILE 32
#define HALO 2
#define LH (TILE + HALO)        // 34 rows: tile + bottom halo (no top halo needed)
#define LW (TILE + 2 * HALO)    // 36 cols

typedef float v2f __attribute__((ext_vector_type(2)));

constexpr float W_IN  = 1.0f / 9.0f + 0.02f;   // 3x3 ring: 1/9 + 0.5/25
constexpr float W_OUT = 0.02f;                 // 5x5 outer ring: 0.5/25
// OOB cells are staged as (0,0,0,0). Clean path then yields for such a pair:
// d = P_log1p(1) + Q_exp(0) + eps = 0.69250215 + 0.99982756 + 1e-6 = 1.6923307
constexpr float INV_D_OOB = 0.59090266f;

__device__ __forceinline__ v2f vsp(float x) { v2f r; r.x = x; r.y = x; return r; }

// Two directed-pair fractions vs common center ca, merged into one (N, D).
// All FMA-heavy math on 2-wide vectors -> v_pk_fma_f32 candidates.
__device__ __forceinline__ void pair2(const float4 ca, const float4 cb1, const float4 cb2,
                                      float w1, float w2, float& N, float& D) {
    v2f qx; qx.x = cb1.x; qx.y = cb2.x;
    v2f qy; qy.x = cb1.y; qy.y = cb2.y;
    v2f qz; qz.x = cb1.z; qz.y = cb2.z;
    v2f qw; qw.x = cb1.w; qw.y = cb2.w;

    const v2f j = qx * vsp(ca.x);
    v2f u;
    u.x = __expf(-fabsf(j.x));
    u.y = __expf(-fabsf(j.y));
    // ln(1+u), u in (0,1]: deg-4 centered Taylor, |err| <= 8.2e-4
    const v2f t = (u - vsp(0.5f)) * vsp(0.66666667f);
    v2f s = __builtin_elementwise_fma(t, vsp(-0.25f), vsp(0.33333333f));
    s = __builtin_elementwise_fma(s, t, vsp(-0.5f));
    s = __builtin_elementwise_fma(s, t, vsp(1.0f));
    v2f sp = __builtin_elementwise_fma(s, t, vsp(0.40546511f));
    sp = sp + __builtin_elementwise_max(j, vsp(0.0f));      // softplus(j)
    const v2f m = sp - j * (qy * vsp(ca.y));                // mutual
    // exp(-gg) + eps, gg in [0,1): deg-4 centered Taylor, |err| <= 2.6e-4
    const v2f z = qz * vsp(ca.z) - vsp(0.5f);
    v2f e = __builtin_elementwise_fma(z, vsp(0.041666667f), vsp(-0.16666667f));
    e = __builtin_elementwise_fma(e, z, vsp(0.5f));
    e = __builtin_elementwise_fma(e, z, vsp(-1.0f));
    e = __builtin_elementwise_fma(e, z, vsp(1.0f));
    const v2f d = __builtin_elementwise_fma(e, vsp(0.60653066f), m + vsp(1e-6f));
    v2f wv; wv.x = w1; wv.y = w2;
    const v2f n = (qw + vsp(ca.w)) * wv;
    N = n.x * d.y + n.y * d.x;
    D = d.x * d.y;
}

__global__ __launch_bounds__(256) void scloss_main(
    const float* __restrict__ pred, const float* __restrict__ target,
    float* __restrict__ out, int B, int H, int W, double inv_cnt) {
    __shared__ float4 sh[LH * LW];   // (p, t, sigmoid(p), bce); OOB cells = zeros

    const int tilesX = W / TILE;
    const int tilesPer = tilesX * (H / TILE);
    const int b = blockIdx.x / tilesPer;
    const int tile = blockIdx.x % tilesPer;
    const int ty0 = (tile / tilesX) * TILE;
    const int tx0 = (tile % tilesX) * TILE;

    const float* pbase = pred + (size_t)b * H * W;
    const float* tbase = target + (size_t)b * H * W;
    const int tid = threadIdx.x;

    // Stage: one exp serves sigmoid AND softplus.
    for (int idx = tid; idx < LH * LW; idx += 256) {
        const int cy = idx / LW, cx = idx % LW;
        const int gy = ty0 + cy;
        const int gx = tx0 + cx - HALO;
        float p = 0.f, t = 0.f, g = 0.f, bce = 0.f;
        if (gy < H && gx >= 0 && gx < W) {
            p = pbase[gy * W + gx];
            t = tbase[gy * W + gx];
            const float en = __expf(-fabsf(p));
            const float inv = __builtin_amdgcn_rcpf(1.f + en);
            g = (p >= 0.f) ? inv : en * inv;       // sigmoid(p)
            const float tt = (en - 0.5f) * 0.66666667f;
            float ss = fmaf(tt, -0.25f, 0.33333333f);
            ss = fmaf(ss, tt, -0.5f);
            ss = fmaf(ss, tt, 1.0f);
            bce = fmaf(ss, tt, 0.40546511f) + fmaxf(p, 0.f) - p * t;
        }
        sh[idx] = make_float4(p, t, g, bce);
    }
    __syncthreads();

    const int px = tid & 31;
    const int py0 = tid >> 5;
    float acc = 0.f;

    const bool edge = (tx0 == 0) | (tx0 + TILE == W) | (ty0 == 0) | (ty0 + TILE == H);

    constexpr int pdy[12] = {0, 0, 1, 1, 1, 1, 1, 2, 2, 2, 2, 2};
    constexpr int pdx[12] = {1, 2, -2, -1, 0, 1, 2, -2, -1, 0, 1, 2};
    constexpr float pw12[12] = {W_IN, W_OUT, W_OUT, W_IN, W_IN, W_IN,
                                W_OUT, W_OUT, W_OUT, W_OUT, W_OUT, W_OUT};

    #pragma unroll
    for (int r = 0; r < 4; ++r) {
        const int ay = py0 + r * 8;
        const float4* base = &sh[ay * LW + px + HALO];
        const float4 ca = base[0];

        // self term as a scalar fraction (j >= 0 so max(j,0) = j)
        const float j0 = ca.x * ca.x;
        const float u0 = __expf(-j0);
        const float t0 = (u0 - 0.5f) * 0.66666667f;
        float s0 = fmaf(t0, -0.25f, 0.33333333f);
        s0 = fmaf(s0, t0, -0.5f);
        s0 = fmaf(s0, t0, 1.0f);
        const float sp0 = fmaf(s0, t0, 0.40546511f) + j0;
        const float m0 = sp0 - j0 * (ca.y * ca.y);
        const float z0 = ca.z * ca.z - 0.5f;
        float e0 = fmaf(z0, 0.041666667f, -0.16666667f);
        e0 = fmaf(e0, z0, 0.5f);
        e0 = fmaf(e0, z0, -1.0f);
        e0 = fmaf(e0, z0, 1.0f);
        const float d0 = fmaf(e0, 0.60653066f, m0 + 1e-6f);
        const float n0 = W_IN * ca.w;

        // 6 packed pair-groups covering the 12 half-plane offsets
        float N1, D1, N2, D2, N3, D3, N4, D4, N5, D5, N6, D6;
        pair2(ca, base[1],          base[2],          W_IN,  W_OUT, N1, D1); // (0,1)(0,2)
        pair2(ca, base[LW - 2],     base[LW - 1],     W_OUT, W_IN,  N2, D2); // (1,-2)(1,-1)
        pair2(ca, base[LW],         base[LW + 1],     W_IN,  W_IN,  N3, D3); // (1,0)(1,1)
        pair2(ca, base[LW + 2],     base[2 * LW - 2], W_OUT, W_OUT, N4, D4); // (1,2)(2,-2)
        pair2(ca, base[2 * LW - 1], base[2 * LW],     W_OUT, W_OUT, N5, D5); // (2,-1)(2,0)
        pair2(ca, base[2 * LW + 1], base[2 * LW + 2], W_OUT, W_OUT, N6, D6); // (2,1)(2,2)

        // Balanced fraction-merge tree: 7 fractions -> one rcp per row.
        const float Na = n0 * D1 + N1 * d0, Da = d0 * D1;
        const float Nb = N2 * D3 + N3 * D2, Db = D2 * D3;
        const float Nc = N4 * D5 + N5 * D4, Dc = D4 * D5;
        const float Nd = Na * Db + Nb * Da, Dd = Da * Db;
        const float Ne = Nc * D6 + N6 * Dc, De = Dc * D6;
        const float Nf = Nd * De + Ne * Dd, Df = Dd * De;
        acc += Nf * __builtin_amdgcn_rcpf(Df);

        // Edge tiles only (block-uniform): closed-form corrections.
        // +o OOB: clean path added w*bce_a/D_OOB, should be w  -> add w*(1 - bce_a/D_OOB)
        // -o OOB: pair owner a-o doesn't exist               -> add w
        if (edge) {
            const int gy = ty0 + ay, gx = tx0 + px;
            #pragma unroll
            for (int k = 0; k < 12; ++k) {
                if (gy + pdy[k] >= H || gx + pdx[k] < 0 || gx + pdx[k] >= W)
                    acc += pw12[k] * (1.f - ca.w * INV_D_OOB);
                if (gy - pdy[k] < 0 || gx - pdx[k] < 0 || gx - pdx[k] >= W)
                    acc += pw12[k];
            }
        }
    }

    // Block reduction -> one float atomic per block (pre-scaled).
    #pragma unroll
    for (int off = 32; off > 0; off >>= 1)
        acc += __shfl_down(acc, off, 64);
    __shared__ double wsum[4];
    if ((tid & 63) == 0) wsum[tid >> 6] = (double)acc;
    __syncthreads();
    if (tid == 0) {
        const double s = wsum[0] + wsum[1] + wsum[2] + wsum[3];
        atomicAdd(out, (float)(s * inv_cnt));
    }
}

extern "C" void kernel_launch(void* const* d_in, const int* in_sizes, int n_in,
                              void* d_out, int out_size, void* d_ws, size_t ws_size,
                              hipStream_t stream) {
    const float* pred   = (const float*)d_in[0];
    const float* target = (const float*)d_in[1];
    float* out = (float*)d_out;

    const int H = 512, W = 512;
    const int B = in_sizes[0] / (H * W);
    const int nblocks = B * (H / TILE) * (W / TILE);   // 2048 for B=8

    hipMemsetAsync(out, 0, sizeof(float), stream);
    scloss_main<<<nblocks, 256, 0, stream>>>(pred, target, out, B, H, W,
                                             1.0 / ((double)B * H * W));
}